// Round 2
// baseline (296.171 us; speedup 1.0000x reference)
//
#include <hip/hip_runtime.h>
#include <stdint.h>

#define Bb 8
#define Ss 2048
#define Dd 512

typedef _Float16 half8 __attribute__((ext_vector_type(8)));
typedef float floatx4 __attribute__((ext_vector_type(4)));

// ---------------- conversion kernels ----------------
__global__ void conv_x_kernel(const float* __restrict__ x, _Float16* __restrict__ xb) {
    int i = (blockIdx.x * 256 + threadIdx.x) * 8;
    float4 a = *(const float4*)(x + i);
    float4 b = *(const float4*)(x + i + 4);
    half8 h;
    h[0] = (_Float16)a.x; h[1] = (_Float16)a.y; h[2] = (_Float16)a.z; h[3] = (_Float16)a.w;
    h[4] = (_Float16)b.x; h[5] = (_Float16)b.y; h[6] = (_Float16)b.z; h[7] = (_Float16)b.w;
    *(half8*)(xb + i) = h;
}

// transpose + convert one 512x512 weight matrix: Wt[e][d] = W[d][e]
__global__ void conv_w_kernel(const float* __restrict__ W, _Float16* __restrict__ Wt) {
    __shared__ float t[32][33];
    int c0 = blockIdx.x * 32, r0 = blockIdx.y * 32;
    int lx = threadIdx.x & 31, ly = threadIdx.x >> 5;  // ly 0..7
#pragma unroll
    for (int i = 0; i < 32; i += 8)
        t[ly + i][lx] = W[(size_t)(r0 + ly + i) * Dd + c0 + lx];
    __syncthreads();
#pragma unroll
    for (int i = 0; i < 32; i += 8)
        Wt[(size_t)(c0 + ly + i) * Dd + r0 + lx] = (_Float16)t[lx][ly + i];
}

// ---------------- fused QKV projection GEMM ----------------
__device__ __forceinline__ void gl_lds16(const _Float16* g, _Float16* l) {
    __builtin_amdgcn_global_load_lds(
        (__attribute__((address_space(1))) void*)(g),
        (__attribute__((address_space(3))) void*)(l), 16, 0, 0);
}

__launch_bounds__(256)
__global__ void proj_kernel(const _Float16* __restrict__ xb,
                            const _Float16* __restrict__ wt,   // [3][512][512] transposed
                            const float* __restrict__ bq,
                            const float* __restrict__ bk,
                            const float* __restrict__ bv,
                            _Float16* __restrict__ qo,
                            _Float16* __restrict__ ko,
                            _Float16* __restrict__ vto) {
    __shared__ __align__(16) _Float16 At[128 * 32];
    __shared__ __align__(16) _Float16 Bt[128 * 32];
    __shared__ __align__(16) _Float16 R[128 * 136];  // repack tile (stride 136: 16B-aligned rows)
    const int pz = blockIdx.z;
    const _Float16* W = wt + (size_t)pz * Dd * Dd;
    const float* bias = (pz == 0) ? bq : ((pz == 1) ? bk : bv);
    const int tid = threadIdx.x;
    const int wv = tid >> 6, lane = tid & 63;
    const int m0 = blockIdx.x * 128, n0 = blockIdx.y * 128;
    const int li = wv * 2;
    const int srow = lane >> 2;       // 0..15
    const int scol = (lane & 3) * 8;  // 0,8,16,24
    const int wm = (wv & 1) * 64, wn = (wv >> 1) * 64;
    const int lr = lane & 15, lq = lane >> 4;
    floatx4 acc[4][4] = {};
    for (int kk = 0; kk < Dd; kk += 32) {
#pragma unroll
        for (int inst = 0; inst < 2; ++inst) {
            int r = (li + inst) * 16 + srow;
            gl_lds16(xb + (size_t)(m0 + r) * Dd + kk + scol, At + (li + inst) * 512 + lane * 8);
            gl_lds16(W + (size_t)(n0 + r) * Dd + kk + scol, Bt + (li + inst) * 512 + lane * 8);
        }
        __syncthreads();
        half8 af[4], bf[4];
#pragma unroll
        for (int mi = 0; mi < 4; ++mi)
            af[mi] = *(const half8*)&At[(wm + mi * 16 + lr) * 32 + lq * 8];
#pragma unroll
        for (int ni = 0; ni < 4; ++ni)
            bf[ni] = *(const half8*)&Bt[(wn + ni * 16 + lr) * 32 + lq * 8];
#pragma unroll
        for (int mi = 0; mi < 4; ++mi)
#pragma unroll
            for (int ni = 0; ni < 4; ++ni)
                acc[mi][ni] = __builtin_amdgcn_mfma_f32_16x16x32_f16(af[mi], bf[ni], acc[mi][ni], 0, 0, 0);
        __syncthreads();
    }
    // ---- epilogue: bias + repack through LDS, then coalesced half8 stores ----
#pragma unroll
    for (int ni = 0; ni < 4; ++ni) {
        const int gn_l = wn + ni * 16 + lr;
        const float bb = bias[n0 + gn_l];
#pragma unroll
        for (int mi = 0; mi < 4; ++mi) {
#pragma unroll
            for (int rr = 0; rr < 4; ++rr) {
                const int gm_l = wm + mi * 16 + lq * 4 + rr;
                const float v = acc[mi][ni][rr] + bb;
                if (pz == 2) R[gn_l * 136 + gm_l] = (_Float16)v;   // v: transposed layout
                else         R[gm_l * 136 + gn_l] = (_Float16)v;   // q,k: row-major
            }
        }
    }
    __syncthreads();
    const int row = tid >> 1, hf = tid & 1;
    _Float16* dst;
    if (pz == 0)      dst = qo + (size_t)(m0 + row) * Dd + n0 + hf * 64;
    else if (pz == 1) dst = ko + (size_t)(m0 + row) * Dd + n0 + hf * 64;
    else              dst = vto + ((size_t)(m0 >> 11) * Dd + n0 + row) * Ss + (m0 & 2047) + hf * 64;
#pragma unroll
    for (int j = 0; j < 8; ++j)
        *(half8*)(dst + j * 8) = *(const half8*)&R[row * 136 + hf * 64 + j * 8];
}

// ---------------- flash attention v3: 64-key tiles, padded K LDS, early V loads ----------------
// Grid (B, S/64): batch fastest-varying -> all 32 q-tile blocks of a batch land on
// one XCD (round-robin dispatch) => K/V/Q stay L2-resident (FETCH 25MB, verified r1).
// 8 waves, 64 Q-rows/block, key-tile 64, 33 iters, lagged PV (one barrier/iter).
// scores: 2 row-groups(32 rows) x 4 col-groups(16 keys); Q resident 32x512 in regs;
//   each K-fragment ds_read feeds 2 MFMAs; FOUR 8-deep MFMA chains (s0/s1 x ks&1).
// K LDS: padded row stride 520 halves (1040B) -> kf ds_read_b128 bank-optimal
//   (bank = 4*(lr+lq) mod 32, 8 lanes per 4-bank group = conflict-free b128).
// V: read directly from global/L2 as B-fragments ([D][S] layout is exact B layout).
//   ALL 8 V-frags for PV(kt-1) issued right after the barrier, BEFORE the K-DMA
//   issue => vmcnt wait for V does not drain next-tile K prefetch (in-order counter),
//   and V gets the whole scores phase of latency cover.
// LDS: K 2x64x520 (133120 B) + P 2x64x72 (18432 B) + lsum (1 KB) = 152.6 KB, 1 block/CU.
#define KSTR 520   // K row stride (halves)
#define PSTR 72    // P row stride (halves): 144 B = 16B-aligned, bank-offset 4/row
__launch_bounds__(512, 2)
__global__ void attn_kernel(const _Float16* __restrict__ q,
                            const _Float16* __restrict__ k,
                            const _Float16* __restrict__ vt,
                            float* __restrict__ out) {
    __shared__ __align__(16) _Float16 Klds[2 * 64 * KSTR];
    __shared__ __align__(16) _Float16 P[2 * 64 * PSTR];
    __shared__ float lsum[4][64];
    const int b = blockIdx.x;            // batch -> XCD affinity
    const int qrow0 = blockIdx.y * 64;
    const int tid = threadIdx.x;
    const int wv = tid >> 6, lane = tid & 63;
    const int lr = lane & 15, lq = lane >> 4;
    const int rg = wv >> 2, cg = wv & 3;  // scores roles
    const int d = wv;                     // PV role: 64 D-cols per wave
    const _Float16* Qb = q + (size_t)b * Ss * Dd;
    const _Float16* Kb = k + (size_t)b * Ss * Dd;
    const _Float16* Vb = vt + (size_t)b * Dd * Ss;

    // Q fragments: 32 rows x 512 D, kernel-resident
    half8 qf[2][16];
#pragma unroll
    for (int t = 0; t < 2; ++t)
#pragma unroll
        for (int ks = 0; ks < 16; ++ks)
            qf[t][ks] = *(const half8*)&Qb[(size_t)(qrow0 + rg * 32 + t * 16 + lr) * Dd + ks * 32 + lq * 8];

    // prologue: stage K tile 0 into buffer 0 (wave stages rows wv*8..wv*8+7, linear rows)
#pragma unroll
    for (int j = 0; j < 8; ++j)
        gl_lds16(Kb + (size_t)(wv * 8 + j) * Dd + lane * 8,
                 Klds + (wv * 8 + j) * KSTR + lane * 8);

    const _Float16* Kc0 = Klds + (cg * 16 + lr) * KSTR + lq * 8;
    const _Float16* vbl = Vb + (size_t)(d * 64 + lr) * Ss + lq * 8;

    floatx4 o[4][4] = {};
    float lp[8] = {0.f, 0.f, 0.f, 0.f, 0.f, 0.f, 0.f, 0.f};
    const float c1 = 0.044194173824159216f * 1.4426950408889634f;  // (1/sqrt(512))*log2(e)
    const float c2 = 12.0f * 1.4426950408889634f;                  // static shift

    for (int kt = 0; kt <= 32; ++kt) {
        const int cur = kt & 1, prv = cur ^ 1;
        __syncthreads();  // K DMA consumed here is a full compute-phase old
        // ---- V B-fragments for PV(kt-1): issue FIRST (before K-DMA) ----
        half8 vv[8];
        if (kt > 0) {
            const _Float16* vp = vbl + (size_t)(kt - 1) * 64;
#pragma unroll
            for (int h = 0; h < 2; ++h)
#pragma unroll
                for (int ct = 0; ct < 4; ++ct)
                    vv[h * 4 + ct] = *(const half8*)(vp + (size_t)ct * (16 * Ss) + h * 32);
        }
        if (kt < 32) {
            if (kt < 31) {
                // async-stage K tile kt+1 into the other buffer
                const _Float16* ksrc = Kb + (size_t)((kt + 1) * 64 + wv * 8) * Dd + lane * 8;
                _Float16* kdst = Klds + prv * (64 * KSTR) + (wv * 8) * KSTR + lane * 8;
#pragma unroll
                for (int j = 0; j < 8; ++j)
                    gl_lds16(ksrc + (size_t)j * Dd, kdst + j * KSTR);
            }
            // ---- scores(kt): 32 rows x 16 keys per wave; four 8-deep MFMA chains ----
            const _Float16* Kc = Kc0 + cur * (64 * KSTR);
            floatx4 s0[2] = {}, s1[2] = {};
#pragma unroll
            for (int ks = 0; ks < 16; ++ks) {
                half8 kf = *(const half8*)(Kc + ks * 32);
                s0[ks & 1] = __builtin_amdgcn_mfma_f32_16x16x32_f16(qf[0][ks], kf, s0[ks & 1], 0, 0, 0);
                s1[ks & 1] = __builtin_amdgcn_mfma_f32_16x16x32_f16(qf[1][ks], kf, s1[ks & 1], 0, 0, 0);
            }
            _Float16* Pc = P + cur * (64 * PSTR);
#pragma unroll
            for (int i = 0; i < 4; ++i) {
                float p0 = __builtin_amdgcn_exp2f((s0[0][i] + s0[1][i]) * c1 - c2);
                float p1 = __builtin_amdgcn_exp2f((s1[0][i] + s1[1][i]) * c1 - c2);
                lp[i] += p0;
                lp[4 + i] += p1;
                Pc[(rg * 32 + lq * 4 + i) * PSTR + cg * 16 + lr] = (_Float16)p0;
                Pc[(rg * 32 + 16 + lq * 4 + i) * PSTR + cg * 16 + lr] = (_Float16)p1;
            }
        }
        if (kt > 0) {
            // ---- PV(kt-1): o(64 rows x wave's 64 D-cols) += P[prv] * V ----
            const _Float16* Pp = P + prv * (64 * PSTR);
#pragma unroll
            for (int h = 0; h < 2; ++h) {
#pragma unroll
                for (int rt = 0; rt < 4; ++rt) {
                    half8 af = *(const half8*)&Pp[(rt * 16 + lr) * PSTR + h * 32 + lq * 8];
#pragma unroll
                    for (int ct = 0; ct < 4; ++ct)
                        o[rt][ct] = __builtin_amdgcn_mfma_f32_16x16x32_f16(af, vv[h * 4 + ct], o[rt][ct], 0, 0, 0);
                }
            }
        }
    }

    // ---- row-sum combine across the 4 col-groups ----
#pragma unroll
    for (int i = 0; i < 8; ++i) {
#pragma unroll
        for (int m = 1; m < 16; m <<= 1)
            lp[i] += __shfl_xor(lp[i], m);
    }
    if (lr == 0) {
#pragma unroll
        for (int t = 0; t < 2; ++t)
#pragma unroll
            for (int i = 0; i < 4; ++i)
                lsum[cg][rg * 32 + t * 16 + lq * 4 + i] = lp[t * 4 + i];
    }
    __syncthreads();

    // ---- epilogue: wave d writes its 64 D-cols for all 64 rows ----
    float* Ob = out + ((size_t)b * Ss + qrow0) * Dd;
#pragma unroll
    for (int rt = 0; rt < 4; ++rt) {
#pragma unroll
        for (int i = 0; i < 4; ++i) {
            const int rl = rt * 16 + lq * 4 + i;
            const float inv = 1.0f / (lsum[0][rl] + lsum[1][rl] + lsum[2][rl] + lsum[3][rl]);
#pragma unroll
            for (int ct = 0; ct < 4; ++ct)
                Ob[(size_t)rl * Dd + d * 64 + ct * 16 + lr] = o[rt][ct][i] * inv;
        }
    }
}

// ---------------- launch ----------------
extern "C" void kernel_launch(void* const* d_in, const int* in_sizes, int n_in,
                              void* d_out, int out_size, void* d_ws, size_t ws_size,
                              hipStream_t stream) {
    const float* x  = (const float*)d_in[0];
    const float* Wq = (const float*)d_in[1];
    const float* bq = (const float*)d_in[2];
    const float* Wk = (const float*)d_in[3];
    const float* bk = (const float*)d_in[4];
    const float* Wv = (const float*)d_in[5];
    const float* bv = (const float*)d_in[6];

    const size_t NE = (size_t)Bb * Ss * Dd;  // 8.39M elements
    _Float16* xb  = (_Float16*)d_ws;
    _Float16* qw  = xb + NE;
    _Float16* kw  = qw + NE;
    _Float16* vtw = kw + NE;
    _Float16* wt  = vtw + NE;  // 3 * 512*512

    conv_x_kernel<<<dim3((unsigned)(NE / 2048)), 256, 0, stream>>>(x, xb);
    conv_w_kernel<<<dim3(16, 16), 256, 0, stream>>>(Wq, wt);
    conv_w_kernel<<<dim3(16, 16), 256, 0, stream>>>(Wk, wt + Dd * Dd);
    conv_w_kernel<<<dim3(16, 16), 256, 0, stream>>>(Wv, wt + 2 * Dd * Dd);
    proj_kernel<<<dim3(128, 4, 3), 256, 0, stream>>>(xb, wt, bq, bk, bv, qw, kw, vtw);
    attn_kernel<<<dim3(8, 32), 512, 0, stream>>>(qw, kw, vtw, (float*)d_out);
}

// Round 3
// 264.701 us; speedup vs baseline: 1.1189x; 1.1189x over previous
//
#include <hip/hip_runtime.h>
#include <stdint.h>

#define Bb 8
#define Ss 2048
#define Dd 512

typedef _Float16 half8 __attribute__((ext_vector_type(8)));
typedef float floatx4 __attribute__((ext_vector_type(4)));

// ---------------- conversion kernels ----------------
__global__ void conv_x_kernel(const float* __restrict__ x, _Float16* __restrict__ xb) {
    int i = (blockIdx.x * 256 + threadIdx.x) * 8;
    float4 a = *(const float4*)(x + i);
    float4 b = *(const float4*)(x + i + 4);
    half8 h;
    h[0] = (_Float16)a.x; h[1] = (_Float16)a.y; h[2] = (_Float16)a.z; h[3] = (_Float16)a.w;
    h[4] = (_Float16)b.x; h[5] = (_Float16)b.y; h[6] = (_Float16)b.z; h[7] = (_Float16)b.w;
    *(half8*)(xb + i) = h;
}

// transpose + convert one 512x512 weight matrix: Wt[e][d] = W[d][e]
__global__ void conv_w_kernel(const float* __restrict__ W, _Float16* __restrict__ Wt) {
    __shared__ float t[32][33];
    int c0 = blockIdx.x * 32, r0 = blockIdx.y * 32;
    int lx = threadIdx.x & 31, ly = threadIdx.x >> 5;  // ly 0..7
#pragma unroll
    for (int i = 0; i < 32; i += 8)
        t[ly + i][lx] = W[(size_t)(r0 + ly + i) * Dd + c0 + lx];
    __syncthreads();
#pragma unroll
    for (int i = 0; i < 32; i += 8)
        Wt[(size_t)(c0 + ly + i) * Dd + r0 + lx] = (_Float16)t[lx][ly + i];
}

// ---------------- fused QKV projection GEMM ----------------
__device__ __forceinline__ void gl_lds16(const _Float16* g, _Float16* l) {
    __builtin_amdgcn_global_load_lds(
        (__attribute__((address_space(1))) void*)(g),
        (__attribute__((address_space(3))) void*)(l), 16, 0, 0);
}

__launch_bounds__(256)
__global__ void proj_kernel(const _Float16* __restrict__ xb,
                            const _Float16* __restrict__ wt,   // [3][512][512] transposed
                            const float* __restrict__ bq,
                            const float* __restrict__ bk,
                            const float* __restrict__ bv,
                            _Float16* __restrict__ qo,
                            _Float16* __restrict__ ko,
                            _Float16* __restrict__ vto) {
    __shared__ __align__(16) _Float16 At[128 * 32];
    __shared__ __align__(16) _Float16 Bt[128 * 32];
    __shared__ __align__(16) _Float16 R[128 * 136];  // repack tile (stride 136: 16B-aligned rows)
    const int pz = blockIdx.z;
    const _Float16* W = wt + (size_t)pz * Dd * Dd;
    const float* bias = (pz == 0) ? bq : ((pz == 1) ? bk : bv);
    const int tid = threadIdx.x;
    const int wv = tid >> 6, lane = tid & 63;
    const int m0 = blockIdx.x * 128, n0 = blockIdx.y * 128;
    const int li = wv * 2;
    const int srow = lane >> 2;       // 0..15
    const int scol = (lane & 3) * 8;  // 0,8,16,24
    const int wm = (wv & 1) * 64, wn = (wv >> 1) * 64;
    const int lr = lane & 15, lq = lane >> 4;
    floatx4 acc[4][4] = {};
    for (int kk = 0; kk < Dd; kk += 32) {
#pragma unroll
        for (int inst = 0; inst < 2; ++inst) {
            int r = (li + inst) * 16 + srow;
            gl_lds16(xb + (size_t)(m0 + r) * Dd + kk + scol, At + (li + inst) * 512 + lane * 8);
            gl_lds16(W + (size_t)(n0 + r) * Dd + kk + scol, Bt + (li + inst) * 512 + lane * 8);
        }
        __syncthreads();
        half8 af[4], bf[4];
#pragma unroll
        for (int mi = 0; mi < 4; ++mi)
            af[mi] = *(const half8*)&At[(wm + mi * 16 + lr) * 32 + lq * 8];
#pragma unroll
        for (int ni = 0; ni < 4; ++ni)
            bf[ni] = *(const half8*)&Bt[(wn + ni * 16 + lr) * 32 + lq * 8];
#pragma unroll
        for (int mi = 0; mi < 4; ++mi)
#pragma unroll
            for (int ni = 0; ni < 4; ++ni)
                acc[mi][ni] = __builtin_amdgcn_mfma_f32_16x16x32_f16(af[mi], bf[ni], acc[mi][ni], 0, 0, 0);
        __syncthreads();
    }
    // ---- epilogue: bias + repack through LDS, then coalesced half8 stores ----
#pragma unroll
    for (int ni = 0; ni < 4; ++ni) {
        const int gn_l = wn + ni * 16 + lr;
        const float bb = bias[n0 + gn_l];
#pragma unroll
        for (int mi = 0; mi < 4; ++mi) {
#pragma unroll
            for (int rr = 0; rr < 4; ++rr) {
                const int gm_l = wm + mi * 16 + lq * 4 + rr;
                const float v = acc[mi][ni][rr] + bb;
                if (pz == 2) R[gn_l * 136 + gm_l] = (_Float16)v;   // v: transposed layout
                else         R[gm_l * 136 + gn_l] = (_Float16)v;   // q,k: row-major
            }
        }
    }
    __syncthreads();
    const int row = tid >> 1, hf = tid & 1;
    _Float16* dst;
    if (pz == 0)      dst = qo + (size_t)(m0 + row) * Dd + n0 + hf * 64;
    else if (pz == 1) dst = ko + (size_t)(m0 + row) * Dd + n0 + hf * 64;
    else              dst = vto + ((size_t)(m0 >> 11) * Dd + n0 + row) * Ss + (m0 & 2047) + hf * 64;
#pragma unroll
    for (int j = 0; j < 8; ++j)
        *(half8*)(dst + j * 8) = *(const half8*)&R[row * 136 + hf * 64 + j * 8];
}

// ---------------- flash attention v4: v1 register shape + v2/v3 verified wins ----------------
// Grid (B, S/64): batch fastest-varying -> XCD b owns batch b; K/V L2/L3-resident
// (FETCH 25MB, verified r1/r2). 8 waves, 64 Q-rows/block, key-tile 64, 33 iters.
// REGISTER BUDGET is the binding constraint (r1/r2 lesson: qf[2][16]=128 VGPR pushed
// total unified past 256 -> scratch spills, per-iter 4.7K->12.2K cyc). v4: scores are
// 4 row-groups(16 rows) x 2 col-groups(32 keys): qf[16]=64 VGPR. Total ~200 < 256.
// scores: per wave 32 kf ds_reads / 32 MFMAs, four 8-deep chains (s[nt][ks&1]).
// K LDS: padded KSTR=520 (1040B rows) -> kf ds_read_b128 conflict-free (r2: -57% conf).
// V: read directly from global/L2 as B-fragments; all 8 issued right after the
// barrier BEFORE the K-DMA (in-order vmcnt: PV's wait doesn't drain K prefetch).
// LDS: K 2x64x520 (133120 B) + P 2x64x72 (18432 B) + lsum (512 B) = 152 KB, 1 block/CU.
#define KSTR 520   // K row stride (halves)
#define PSTR 72    // P row stride (halves): 144 B = 16B-aligned
__launch_bounds__(512, 2)
__global__ void attn_kernel(const _Float16* __restrict__ q,
                            const _Float16* __restrict__ k,
                            const _Float16* __restrict__ vt,
                            float* __restrict__ out) {
    __shared__ __align__(16) _Float16 Klds[2 * 64 * KSTR];
    __shared__ __align__(16) _Float16 P[2 * 64 * PSTR];
    __shared__ float lsum[2][64];
    const int b = blockIdx.x;            // batch -> XCD affinity
    const int qrow0 = blockIdx.y * 64;
    const int tid = threadIdx.x;
    const int wv = tid >> 6, lane = tid & 63;
    const int lr = lane & 15, lq = lane >> 4;
    const int rg = wv >> 1, cg = wv & 1;  // scores roles: 4 row-groups x 2 col-groups
    const int d = wv;                     // PV role: 64 D-cols per wave
    const _Float16* Qb = q + (size_t)b * Ss * Dd;
    const _Float16* Kb = k + (size_t)b * Ss * Dd;
    const _Float16* Vb = vt + (size_t)b * Dd * Ss;

    // Q fragments: 16 rows x 512 D per wave, kernel-resident (64 VGPR)
    half8 qf[16];
#pragma unroll
    for (int ks = 0; ks < 16; ++ks)
        qf[ks] = *(const half8*)&Qb[(size_t)(qrow0 + rg * 16 + lr) * Dd + ks * 32 + lq * 8];

    // prologue: stage K tile 0 into buffer 0 (wave stages rows wv*8..wv*8+7, linear rows)
#pragma unroll
    for (int j = 0; j < 8; ++j)
        gl_lds16(Kb + (size_t)(wv * 8 + j) * Dd + lane * 8,
                 Klds + (wv * 8 + j) * KSTR + lane * 8);

    const _Float16* Kc0 = Klds + (cg * 32 + lr) * KSTR + lq * 8;
    const _Float16* vbl = Vb + (size_t)(d * 64 + lr) * Ss + lq * 8;

    floatx4 o[4][4] = {};
    float lp[4] = {0.f, 0.f, 0.f, 0.f};
    const float c1 = 0.044194173824159216f * 1.4426950408889634f;  // (1/sqrt(512))*log2(e)
    const float c2 = 12.0f * 1.4426950408889634f;                  // static shift

    for (int kt = 0; kt <= 32; ++kt) {
        const int cur = kt & 1, prv = cur ^ 1;
        __syncthreads();  // K DMA consumed here is a full compute-phase old
        // ---- V B-fragments for PV(kt-1): issue FIRST (before K-DMA) ----
        half8 vv[8];
        if (kt > 0) {
            const _Float16* vp = vbl + (size_t)(kt - 1) * 64;
#pragma unroll
            for (int h = 0; h < 2; ++h)
#pragma unroll
                for (int ct = 0; ct < 4; ++ct)
                    vv[h * 4 + ct] = *(const half8*)(vp + (size_t)ct * (16 * Ss) + h * 32);
        }
        if (kt < 32) {
            if (kt < 31) {
                // async-stage K tile kt+1 into the other buffer
                const _Float16* ksrc = Kb + (size_t)((kt + 1) * 64 + wv * 8) * Dd + lane * 8;
                _Float16* kdst = Klds + prv * (64 * KSTR) + (wv * 8) * KSTR + lane * 8;
#pragma unroll
                for (int j = 0; j < 8; ++j)
                    gl_lds16(ksrc + (size_t)j * Dd, kdst + j * KSTR);
            }
            // ---- scores(kt): 16 rows x 32 keys per wave; four 8-deep MFMA chains ----
            const _Float16* Kc = Kc0 + cur * (64 * KSTR);
            floatx4 s[2][2] = {};
#pragma unroll
            for (int nt = 0; nt < 2; ++nt) {
                const _Float16* Kn = Kc + nt * (16 * KSTR);
#pragma unroll
                for (int ks = 0; ks < 16; ++ks) {
                    half8 kf = *(const half8*)(Kn + ks * 32);
                    s[nt][ks & 1] = __builtin_amdgcn_mfma_f32_16x16x32_f16(qf[ks], kf, s[nt][ks & 1], 0, 0, 0);
                }
            }
            _Float16* Pc = P + cur * (64 * PSTR);
#pragma unroll
            for (int nt = 0; nt < 2; ++nt) {
#pragma unroll
                for (int i = 0; i < 4; ++i) {
                    float p = __builtin_amdgcn_exp2f((s[nt][0][i] + s[nt][1][i]) * c1 - c2);
                    lp[i] += p;
                    Pc[(rg * 16 + lq * 4 + i) * PSTR + cg * 32 + nt * 16 + lr] = (_Float16)p;
                }
            }
        }
        if (kt > 0) {
            // ---- PV(kt-1): o(64 rows x wave's 64 D-cols) += P[prv] * V ----
            const _Float16* Pp = P + prv * (64 * PSTR);
#pragma unroll
            for (int h = 0; h < 2; ++h) {
#pragma unroll
                for (int rt = 0; rt < 4; ++rt) {
                    half8 af = *(const half8*)&Pp[(rt * 16 + lr) * PSTR + h * 32 + lq * 8];
#pragma unroll
                    for (int ct = 0; ct < 4; ++ct)
                        o[rt][ct] = __builtin_amdgcn_mfma_f32_16x16x32_f16(af, vv[h * 4 + ct], o[rt][ct], 0, 0, 0);
                }
            }
        }
    }

    // ---- row-sum combine across the 2 col-groups ----
#pragma unroll
    for (int i = 0; i < 4; ++i) {
#pragma unroll
        for (int m = 1; m < 16; m <<= 1)
            lp[i] += __shfl_xor(lp[i], m);
    }
    if (lr == 0) {
#pragma unroll
        for (int i = 0; i < 4; ++i)
            lsum[cg][rg * 16 + lq * 4 + i] = lp[i];
    }
    __syncthreads();

    // ---- epilogue: wave d writes its 64 D-cols for all 64 rows ----
    float* Ob = out + ((size_t)b * Ss + qrow0) * Dd;
#pragma unroll
    for (int rt = 0; rt < 4; ++rt) {
#pragma unroll
        for (int i = 0; i < 4; ++i) {
            const int rl = rt * 16 + lq * 4 + i;
            const float inv = 1.0f / (lsum[0][rl] + lsum[1][rl]);
#pragma unroll
            for (int ct = 0; ct < 4; ++ct)
                Ob[(size_t)rl * Dd + d * 64 + ct * 16 + lr] = o[rt][ct][i] * inv;
        }
    }
}

// ---------------- launch ----------------
extern "C" void kernel_launch(void* const* d_in, const int* in_sizes, int n_in,
                              void* d_out, int out_size, void* d_ws, size_t ws_size,
                              hipStream_t stream) {
    const float* x  = (const float*)d_in[0];
    const float* Wq = (const float*)d_in[1];
    const float* bq = (const float*)d_in[2];
    const float* Wk = (const float*)d_in[3];
    const float* bk = (const float*)d_in[4];
    const float* Wv = (const float*)d_in[5];
    const float* bv = (const float*)d_in[6];

    const size_t NE = (size_t)Bb * Ss * Dd;  // 8.39M elements
    _Float16* xb  = (_Float16*)d_ws;
    _Float16* qw  = xb + NE;
    _Float16* kw  = qw + NE;
    _Float16* vtw = kw + NE;
    _Float16* wt  = vtw + NE;  // 3 * 512*512

    conv_x_kernel<<<dim3((unsigned)(NE / 2048)), 256, 0, stream>>>(x, xb);
    conv_w_kernel<<<dim3(16, 16), 256, 0, stream>>>(Wq, wt);
    conv_w_kernel<<<dim3(16, 16), 256, 0, stream>>>(Wk, wt + Dd * Dd);
    conv_w_kernel<<<dim3(16, 16), 256, 0, stream>>>(Wv, wt + 2 * Dd * Dd);
    proj_kernel<<<dim3(128, 4, 3), 256, 0, stream>>>(xb, wt, bq, bk, bv, qw, kw, vtw);
    attn_kernel<<<dim3(8, 32), 512, 0, stream>>>(qw, kw, vtw, (float*)d_out);
}

// Round 4
// 260.890 us; speedup vs baseline: 1.1352x; 1.0146x over previous
//
#include <hip/hip_runtime.h>
#include <stdint.h>

#define Bb 8
#define Ss 2048
#define Dd 512

typedef _Float16 half8 __attribute__((ext_vector_type(8)));
typedef float floatx4 __attribute__((ext_vector_type(4)));

// ---------------- conversion kernels ----------------
__global__ void conv_x_kernel(const float* __restrict__ x, _Float16* __restrict__ xb) {
    int i = (blockIdx.x * 256 + threadIdx.x) * 8;
    float4 a = *(const float4*)(x + i);
    float4 b = *(const float4*)(x + i + 4);
    half8 h;
    h[0] = (_Float16)a.x; h[1] = (_Float16)a.y; h[2] = (_Float16)a.z; h[3] = (_Float16)a.w;
    h[4] = (_Float16)b.x; h[5] = (_Float16)b.y; h[6] = (_Float16)b.z; h[7] = (_Float16)b.w;
    *(half8*)(xb + i) = h;
}

// transpose + convert one 512x512 weight matrix: Wt[e][d] = W[d][e]
__global__ void conv_w_kernel(const float* __restrict__ W, _Float16* __restrict__ Wt) {
    __shared__ float t[32][33];
    int c0 = blockIdx.x * 32, r0 = blockIdx.y * 32;
    int lx = threadIdx.x & 31, ly = threadIdx.x >> 5;  // ly 0..7
#pragma unroll
    for (int i = 0; i < 32; i += 8)
        t[ly + i][lx] = W[(size_t)(r0 + ly + i) * Dd + c0 + lx];
    __syncthreads();
#pragma unroll
    for (int i = 0; i < 32; i += 8)
        Wt[(size_t)(c0 + ly + i) * Dd + r0 + lx] = (_Float16)t[lx][ly + i];
}

// ---------------- fused QKV projection GEMM (v2: double-buffered, LDS-unioned) ----------------
__device__ __forceinline__ void gl_lds16(const _Float16* g, _Float16* l) {
    __builtin_amdgcn_global_load_lds(
        (__attribute__((address_space(1))) void*)(g),
        (__attribute__((address_space(3))) void*)(l), 16, 0, 0);
}

// LDS plan: two A/B staging buffers (4x8KB = 32KB) overlaid by the 34.8KB repack
// tile R (only live after the K-loop). Total 34816 B -> 4 blocks/CU (was 51KB/3).
// Pipeline: one barrier per K-step; stage(t+1)->buf^1 issued right after the
// barrier that publishes buf[cur]; compute covers the DMA latency (was: DMA ->
// barrier-drain -> compute with ZERO overlap = the ~2x proj slowdown).
// Hazards: RAW on buf[cur] closed by the barrier's vmcnt(0) drain (all waves
// drain their own DMAs); WAR on buf^1 closed because its readers ran in iter
// t-1, before the top barrier of iter t.
__launch_bounds__(256, 4)
__global__ void proj_kernel(const _Float16* __restrict__ xb,
                            const _Float16* __restrict__ wt,   // [3][512][512] transposed
                            const float* __restrict__ bq,
                            const float* __restrict__ bk,
                            const float* __restrict__ bv,
                            _Float16* __restrict__ qo,
                            _Float16* __restrict__ ko,
                            _Float16* __restrict__ vto) {
    __shared__ __align__(16) unsigned char smem[34816];
    _Float16* R = (_Float16*)smem;                     // [128][136], post-loop only
    const int pz = blockIdx.z;
    const _Float16* W = wt + (size_t)pz * Dd * Dd;
    const float* bias = (pz == 0) ? bq : ((pz == 1) ? bk : bv);
    const int tid = threadIdx.x;
    const int wv = tid >> 6, lane = tid & 63;
    const int m0 = blockIdx.x * 128, n0 = blockIdx.y * 128;
    const int li = wv * 2;
    const int srow = lane >> 2;       // 0..15
    const int scol = (lane & 3) * 8;  // 0,8,16,24
    const int wm = (wv & 1) * 64, wn = (wv >> 1) * 64;
    const int lr = lane & 15, lq = lane >> 4;
    floatx4 acc[4][4] = {};

    // stage tile t into buffer buf: A rows from xb, B rows from W (32 k-elems each)
    auto stage = [&](int t, int buf) {
        _Float16* Ab = (_Float16*)(smem + buf * 16384);
        _Float16* Bt = (_Float16*)(smem + buf * 16384 + 8192);
        const int kk = t * 32;
#pragma unroll
        for (int inst = 0; inst < 2; ++inst) {
            int r = (li + inst) * 16 + srow;
            gl_lds16(xb + (size_t)(m0 + r) * Dd + kk + scol, Ab + (li + inst) * 512 + lane * 8);
            gl_lds16(W + (size_t)(n0 + r) * Dd + kk + scol, Bt + (li + inst) * 512 + lane * 8);
        }
    };

    stage(0, 0);  // prologue
    for (int t = 0; t < 16; ++t) {
        const int cur = t & 1;
        __syncthreads();              // buf[cur] ready; buf[cur^1] readers done
        if (t < 15) stage(t + 1, cur ^ 1);
        const _Float16* Ab = (const _Float16*)(smem + cur * 16384);
        const _Float16* Bt = (const _Float16*)(smem + cur * 16384 + 8192);
        half8 af[4], bf[4];
#pragma unroll
        for (int mi = 0; mi < 4; ++mi)
            af[mi] = *(const half8*)&Ab[(wm + mi * 16 + lr) * 32 + lq * 8];
#pragma unroll
        for (int ni = 0; ni < 4; ++ni)
            bf[ni] = *(const half8*)&Bt[(wn + ni * 16 + lr) * 32 + lq * 8];
#pragma unroll
        for (int mi = 0; mi < 4; ++mi)
#pragma unroll
            for (int ni = 0; ni < 4; ++ni)
                acc[mi][ni] = __builtin_amdgcn_mfma_f32_16x16x32_f16(af[mi], bf[ni], acc[mi][ni], 0, 0, 0);
    }
    __syncthreads();  // staging buffers dead; R may now overwrite them

    // ---- epilogue: bias + repack through LDS, then coalesced half8 stores ----
#pragma unroll
    for (int ni = 0; ni < 4; ++ni) {
        const int gn_l = wn + ni * 16 + lr;
        const float bb = bias[n0 + gn_l];
#pragma unroll
        for (int mi = 0; mi < 4; ++mi) {
#pragma unroll
            for (int rr = 0; rr < 4; ++rr) {
                const int gm_l = wm + mi * 16 + lq * 4 + rr;
                const float v = acc[mi][ni][rr] + bb;
                if (pz == 2) R[gn_l * 136 + gm_l] = (_Float16)v;   // v: transposed layout
                else         R[gm_l * 136 + gn_l] = (_Float16)v;   // q,k: row-major
            }
        }
    }
    __syncthreads();
    const int row = tid >> 1, hf = tid & 1;
    _Float16* dst;
    if (pz == 0)      dst = qo + (size_t)(m0 + row) * Dd + n0 + hf * 64;
    else if (pz == 1) dst = ko + (size_t)(m0 + row) * Dd + n0 + hf * 64;
    else              dst = vto + ((size_t)(m0 >> 11) * Dd + n0 + row) * Ss + (m0 & 2047) + hf * 64;
#pragma unroll
    for (int j = 0; j < 8; ++j)
        *(half8*)(dst + j * 8) = *(const half8*)&R[row * 136 + hf * 64 + j * 8];
}

// ---------------- flash attention: v1 structure (best measured: 126us) + XCD grid ----------------
// Grid (B, S/64): batch fastest-varying -> all 32 q-tile blocks of batch b land on
// XCD b => K/V L2-resident (r1/r2: FETCH 139MB -> 25MB with this grid). ONLY grid
// changed vs the 126us v1 kernel; structure byte-identical (r3 lesson: the K-tile-64
// rewrites were all slower per-key than this shape).
// 512 threads = 8 waves, 64 Q-rows/block, key-tile 32, 65 iters, lagged PV.
// V layout XOR-swizzled in LDS => max 2-way bank aliasing on PV B-frag reads.
// LDS: K 2x32x520 + V 2x512x32 + P 2x64x40 + lsum = 142,848 B -> 1 block/CU.
#define KSTR 520   // K row stride (halves): 1040 B = 16-aligned, 4-bank col step
#define PSTR 40    // P row stride (halves)
__launch_bounds__(512, 2)
__global__ void attn_kernel(const _Float16* __restrict__ q,
                            const _Float16* __restrict__ k,
                            const _Float16* __restrict__ vt,
                            float* __restrict__ out) {
    __shared__ __align__(16) _Float16 Klds[2 * 32 * KSTR];
    __shared__ __align__(16) _Float16 Vlds[2 * 512 * 32];
    __shared__ __align__(16) _Float16 P[2 * 64 * PSTR];
    __shared__ float lsum[2][64];
    const int b = blockIdx.x;            // batch -> XCD affinity
    const int qrow0 = blockIdx.y * 64;
    const int tid = threadIdx.x;
    const int wv = tid >> 6, lane = tid & 63;
    const int lr = lane & 15, lq = lane >> 4;
    const int r = wv >> 1, c = wv & 1;   // score roles: 4 row-groups x 2 col-groups(16)
    const int d = wv;                    // PV role: 8 D-col groups of 64
    const _Float16* Qb = q + (size_t)b * Ss * Dd;
    const _Float16* Kb = k + (size_t)b * Ss * Dd;
    const _Float16* Vb = vt + (size_t)b * Dd * Ss;

    // Q fragments: 16 rows, kernel-resident (64 VGPR)
    half8 qf[16];
#pragma unroll
    for (int s = 0; s < 16; ++s)
        qf[s] = *(const half8*)&Qb[(size_t)(qrow0 + r * 16 + lr) * Dd + s * 32 + lq * 8];

    // staging pointers
    // K: wave stages 4 rows (wv*4+j), one inst = one full row (64 lanes x 16B = 1KB)
    const _Float16* kbase = Kb + (size_t)(wv * 4) * Dd + lane * 8;
    // V: wave stages dcols [wv*64, wv*64+64), lane ll -> local row ll>>2, phys chunk ll&3,
    // logical chunk kl = (ll&3)^((ll>>2)&3)^((ll>>4)&3)  (j-independent)
    const int kl = (lane & 3) ^ ((lane >> 2) & 3) ^ ((lane >> 4) & 3);
    const _Float16* vbase = Vb + (size_t)(wv * 64 + (lane >> 2)) * Ss + kl * 8;
    const int vsw = lq ^ (lr & 3) ^ ((lr >> 2) & 3);  // PV read-side swizzle (lane-only)

    floatx4 o[4][4] = {};
    float lp[4] = {0.f, 0.f, 0.f, 0.f};
    const float c1 = 0.044194173824159216f * 1.4426950408889634f;  // (1/sqrt(512))*log2(e)
    const float c2 = 12.0f * 1.4426950408889634f;                  // static shift

    // prologue: stage K tile 0 into buffer 0
#pragma unroll
    for (int j = 0; j < 4; ++j)
        gl_lds16(kbase + (size_t)j * Dd, Klds + (wv * 4 + j) * KSTR + lane * 8);

    for (int kt = 0; kt <= 64; ++kt) {
        const int cur = kt & 1, prv = cur ^ 1;
        __syncthreads();  // DMAs consumed here are a full iteration old

        if (kt < 64) {
            // ---- issue async staging: K for kt+1, V for kt ----
            if (kt < 63) {
                const _Float16* ks = kbase + (size_t)(kt + 1) * 32 * Dd;
                _Float16* kd = Klds + prv * (32 * KSTR) + wv * 4 * KSTR + lane * 8;
#pragma unroll
                for (int j = 0; j < 4; ++j)
                    gl_lds16(ks + (size_t)j * Dd, kd + j * KSTR);
            }
            {
                const _Float16* vs = vbase + kt * 32;
                _Float16* vd = Vlds + cur * (512 * 32) + wv * 2048 + lane * 8;
#pragma unroll
                for (int j = 0; j < 4; ++j)
                    gl_lds16(vs + (size_t)j * 16 * Ss, vd + j * 512);
            }
            // ---- scores(kt): 16 rows x 16 cols per wave from K[cur] ----
            floatx4 s[2] = {};
            const _Float16* Kc = Klds + cur * (32 * KSTR) + (c * 16 + lr) * KSTR + lq * 8;
#pragma unroll
            for (int kk = 0; kk < 16; ++kk) {
                half8 kf = *(const half8*)(Kc + kk * 32);
                s[kk & 1] = __builtin_amdgcn_mfma_f32_16x16x32_f16(qf[kk], kf, s[kk & 1], 0, 0, 0);
            }
            _Float16* Pc = P + cur * (64 * PSTR);
#pragma unroll
            for (int i = 0; i < 4; ++i) {
                float p = __builtin_amdgcn_exp2f((s[0][i] + s[1][i]) * c1 - c2);
                lp[i] += p;
                Pc[(r * 16 + lq * 4 + i) * PSTR + c * 16 + lr] = (_Float16)p;
            }
        }
        if (kt > 0) {
            // ---- PV(kt-1): o(64 rows x wave's 64 D-cols) += P[prv] * V[prv] ----
            const _Float16* Pp = P + prv * (64 * PSTR);
            const _Float16* Vp = Vlds + prv * (512 * 32);
            half8 af[4];
#pragma unroll
            for (int m = 0; m < 4; ++m)
                af[m] = *(const half8*)&Pp[(m * 16 + lr) * PSTR + lq * 8];
#pragma unroll
            for (int nt = 0; nt < 4; ++nt) {
                half8 vf = *(const half8*)&Vp[(d * 64 + nt * 16 + lr) * 32 + vsw * 8];
#pragma unroll
                for (int m = 0; m < 4; ++m)
                    o[m][nt] = __builtin_amdgcn_mfma_f32_16x16x32_f16(af[m], vf, o[m][nt], 0, 0, 0);
            }
        }
    }

    // ---- row-sum combine across the two col-groups ----
#pragma unroll
    for (int i = 0; i < 4; ++i) {
#pragma unroll
        for (int m = 1; m < 16; m <<= 1)
            lp[i] += __shfl_xor(lp[i], m);
    }
    if (lr == 0) {
#pragma unroll
        for (int i = 0; i < 4; ++i)
            lsum[c][r * 16 + lq * 4 + i] = lp[i];
    }
    __syncthreads();

    // ---- epilogue: wave d writes its 64 D-cols for all 64 rows ----
    float* Ob = out + ((size_t)b * Ss + qrow0) * Dd;
#pragma unroll
    for (int m = 0; m < 4; ++m) {
#pragma unroll
        for (int i = 0; i < 4; ++i) {
            const int rl = m * 16 + lq * 4 + i;
            const float inv = 1.0f / (lsum[0][rl] + lsum[1][rl]);
#pragma unroll
            for (int nt = 0; nt < 4; ++nt)
                Ob[(size_t)rl * Dd + d * 64 + nt * 16 + lr] = o[m][nt][i] * inv;
        }
    }
}

// ---------------- launch ----------------
extern "C" void kernel_launch(void* const* d_in, const int* in_sizes, int n_in,
                              void* d_out, int out_size, void* d_ws, size_t ws_size,
                              hipStream_t stream) {
    const float* x  = (const float*)d_in[0];
    const float* Wq = (const float*)d_in[1];
    const float* bq = (const float*)d_in[2];
    const float* Wk = (const float*)d_in[3];
    const float* bk = (const float*)d_in[4];
    const float* Wv = (const float*)d_in[5];
    const float* bv = (const float*)d_in[6];

    const size_t NE = (size_t)Bb * Ss * Dd;  // 8.39M elements
    _Float16* xb  = (_Float16*)d_ws;
    _Float16* qw  = xb + NE;
    _Float16* kw  = qw + NE;
    _Float16* vtw = kw + NE;
    _Float16* wt  = vtw + NE;  // 3 * 512*512

    conv_x_kernel<<<dim3((unsigned)(NE / 2048)), 256, 0, stream>>>(x, xb);
    conv_w_kernel<<<dim3(16, 16), 256, 0, stream>>>(Wq, wt);
    conv_w_kernel<<<dim3(16, 16), 256, 0, stream>>>(Wk, wt + Dd * Dd);
    conv_w_kernel<<<dim3(16, 16), 256, 0, stream>>>(Wv, wt + 2 * Dd * Dd);
    proj_kernel<<<dim3(128, 4, 3), 256, 0, stream>>>(xb, wt, bq, bk, bv, qw, kw, vtw);
    attn_kernel<<<dim3(8, 32), 512, 0, stream>>>(qw, kw, vtw, (float*)d_out);
}